// Round 4
// baseline (1348.597 us; speedup 1.0000x reference)
//
#include <hip/hip_runtime.h>
#include <math.h>

// Problem dims (fixed): B*T=32, N=8192, F0=4, F1=8, F2=8, K=3, D0=8, D1=4
constexpr int NN = 8192;
constexpr int NBLK = 512;   // mono-kernel grid; 2 blocks/CU x 256 CUs co-resident

typedef short bh8 __attribute__((ext_vector_type(8)));    // 8 bf16 (4 VGPRs)
typedef float fl4 __attribute__((ext_vector_type(4)));    // 4 fp32 acc

__device__ __forceinline__ float bf2f(ushort h) {
  return __uint_as_float(((uint)h) << 16);
}
__device__ __forceinline__ ushort f2bf(float f) {
  uint u = __float_as_uint(f);
  return (ushort)((u + 0x7fffu + ((u >> 16) & 1u)) >> 16);  // RNE
}

// ---- workspace layout (bytes) ----------------------------------------------
constexpr size_t OFF_P   = 16;                   // 412 fp32 canonical params
constexpr size_t OFF_BAR = 2048;                 // grid-barrier counter (int)
constexpr size_t OFF_XC  = 4096;                 // x bf16 [128][8192]  2 MiB
constexpr size_t OFF_Z1  = OFF_XC + 2097152;     // z1 bf16 [128][8192] 2 MiB
constexpr size_t OFF_Y1  = OFF_Z1 + 2097152;     // y1 bf16 [256][8192] 4 MiB
constexpr size_t OFF_V1  = OFF_Y1 + 4194304;     // v1 bf16 [256][8192] 4 MiB
constexpr size_t OFF_ST  = 33554432;             // St bf16 [8192][8192] 128 MiB
constexpr size_t OFF_CF  = 167772160;            // CF fp32 partials 32 MiB

// param-block offsets (in floats)
constexpr int PO_H1 = 0, PO_B1 = 96, PO_H2 = 104, PO_B2 = 296;
constexpr int PO_W1 = 304, PO_BW1 = 368, PO_W2 = 376, PO_BW2 = 408;

// ---------------------------------------------------------------------------
// pre: detect dtype, canonicalize params to fp32, zero the grid-barrier ctr.
// ---------------------------------------------------------------------------
__global__ __launch_bounds__(256) void pre_kernel(
    const ushort* __restrict__ Sraw,
    const void* h1, const void* b1, const void* h2, const void* b2,
    const void* W1, const void* bw1, const void* W2, const void* bw2,
    char* __restrict__ ws) {
  __shared__ int smax[256];
  __shared__ int sflag;
  const int t = threadIdx.x;
  int mx = 0;
  for (int k = 0; k < 32; ++k) {
    ushort u = Sraw[(size_t)(t * 32 + k) * 2];
    int e = (u >> 7) & 0xff;
    mx = mx > e ? mx : e;
  }
  smax[t] = mx;
  __syncthreads();
  for (int s = 128; s > 0; s >>= 1) {
    if (t < s) smax[t] = smax[t] > smax[t + s] ? smax[t] : smax[t + s];
    __syncthreads();
  }
  if (t == 0) {
    sflag = (smax[0] >= 0x90) ? 1 : 0;
    *(int*)ws = sflag;
    *(int*)(ws + OFF_BAR) = 0;    // ws is poisoned each iter -> must re-zero
  }
  __syncthreads();
  const int f32 = sflag;
  float* pb = (float*)(ws + OFF_P);
  const void* ptrs[8] = {h1, b1, h2, b2, W1, bw1, W2, bw2};
  const int offs[8] = {PO_H1, PO_B1, PO_H2, PO_B2, PO_W1, PO_BW1, PO_W2, PO_BW2};
  const int lens[8] = {96, 8, 192, 8, 64, 8, 32, 4};
  for (int idx = t; idx < 412; idx += 256) {
#pragma unroll
    for (int s = 0; s < 8; ++s) {
      if (idx >= offs[s] && idx < offs[s] + lens[s]) {
        const int j = idx - offs[s];
        pb[idx] = f32 ? ((const float*)ptrs[s])[j]
                      : bf2f(((const ushort*)ptrs[s])[j]);
      }
    }
  }
}

// ---------------------------------------------------------------------------
// Device-scope software grid barrier. Monotonic counter; phase p waits for
// count >= p*NBLK. Release fence + agent-scope RMW publishes this XCD's L2;
// agent-scope acquire load + fence invalidates before proceeding. Bounded
// spin: on pathological loss of residency we break (visible absmax FAIL,
// never a hang).
// ---------------------------------------------------------------------------
__device__ __forceinline__ void gridbar(int* cnt, int phase) {
  __syncthreads();                          // drains all block vmem (vmcnt 0)
  if (threadIdx.x == 0) {
    __threadfence();                        // release: L2 writeback
    __hip_atomic_fetch_add(cnt, 1, __ATOMIC_RELEASE, __HIP_MEMORY_SCOPE_AGENT);
    const int target = phase * NBLK;
    int guard = 0;
    while (__hip_atomic_load(cnt, __ATOMIC_ACQUIRE, __HIP_MEMORY_SCOPE_AGENT) <
           target) {
      __builtin_amdgcn_s_sleep(8);
      if (++guard > (1 << 20)) break;       // ~0.2 s bail-out
    }
    __threadfence();                        // acquire: invalidate stale cache
  }
  __syncthreads();
}

// ---------------------------------------------------------------------------
// GEMM stage (device fn): CP[M,N] = A[M,k-slice] @ St[N,k-slice]^T, bf16,
// m97 shape: 4 waves (2x2), 64x64/wave, acc[4][4]. BK=64 double-buffer,
// XOR-granule DMA staging, counted-vmcnt pipeline (vmcnt(8) steady state).
// sh: 64 KiB LDS base (As = sh, Bs = sh+16384; [2] bufs of 8192 ushorts).
// ---------------------------------------------------------------------------
__device__ __forceinline__ void gemm_stage(const ushort* __restrict__ A,
                                           const ushort* __restrict__ St,
                                           float* __restrict__ CP,
                                           int m0, int n0, int kc0, int KR,
                                           ushort* sh) {
  const int tid = threadIdx.x;
  const int wave = tid >> 6, lane = tid & 63;
  const int lrow = lane & 15, quad = lane >> 4;
  const int wm = (wave & 1) * 64;
  const int wn = (wave >> 1) * 64;

  const ushort* ap[4];
  const ushort* bp[4];
#pragma unroll
  for (int r = 0; r < 4; ++r) {
    const int s = r * 256 + tid;
    const int row = s >> 3, g = (s & 7) ^ (row & 7);
    ap[r] = A + (size_t)(m0 + row) * NN + g * 8;
    bp[r] = St + (size_t)(n0 + row) * NN + g * 8;
  }

  fl4 acc[4][4];
#pragma unroll
  for (int i = 0; i < 4; ++i)
#pragma unroll
    for (int j = 0; j < 4; ++j) acc[i][j] = (fl4){0.f, 0.f, 0.f, 0.f};

#define STAGE(buf, kc)                                                         \
  {                                                                            \
    _Pragma("unroll")                                                          \
    for (int r = 0; r < 4; ++r) {                                              \
      __builtin_amdgcn_global_load_lds(                                        \
          (__attribute__((address_space(1))) void*)(ap[r] + (kc)),             \
          (__attribute__((address_space(3))) void*)                            \
              &sh[(buf) * 8192 + (r * 256 + wave * 64) * 8],                   \
          16, 0, 0);                                                           \
      __builtin_amdgcn_global_load_lds(                                        \
          (__attribute__((address_space(1))) void*)(bp[r] + (kc)),             \
          (__attribute__((address_space(3))) void*)                            \
              &sh[16384 + (buf) * 8192 + (r * 256 + wave * 64) * 8],           \
          16, 0, 0);                                                           \
    }                                                                          \
  }

#define COMPUTE(buf)                                                           \
  {                                                                            \
    _Pragma("unroll")                                                          \
    for (int is = 0; is < 2; ++is) {                                           \
      bh8 af[4], bf[4];                                                        \
      const int G = is * 4 + quad;                                             \
      _Pragma("unroll")                                                        \
      for (int i = 0; i < 4; ++i) {                                            \
        const int row = wm + i * 16 + lrow;                                    \
        af[i] = *(const bh8*)&sh[(buf) * 8192 + row * 64 +                     \
                                 ((G ^ (row & 7)) * 8)];                       \
      }                                                                        \
      _Pragma("unroll")                                                        \
      for (int j = 0; j < 4; ++j) {                                            \
        const int row = wn + j * 16 + lrow;                                    \
        bf[j] = *(const bh8*)&sh[16384 + (buf) * 8192 + row * 64 +             \
                                 ((G ^ (row & 7)) * 8)];                       \
      }                                                                        \
      _Pragma("unroll")                                                        \
      for (int i = 0; i < 4; ++i)                                              \
        _Pragma("unroll")                                                      \
        for (int j = 0; j < 4; ++j)                                            \
          acc[i][j] = __builtin_amdgcn_mfma_f32_16x16x32_bf16(af[i], bf[j],    \
                                                              acc[i][j], 0, 0, 0); \
    }                                                                          \
  }

#define BBAR()                                                                 \
  {                                                                            \
    asm volatile("" ::: "memory");                                             \
    __builtin_amdgcn_s_barrier();                                              \
    asm volatile("" ::: "memory");                                             \
  }

  STAGE(0, kc0)
  STAGE(1, kc0 + 64)
  const int kend = kc0 + KR;
#pragma unroll 1
  for (int kc = kc0; kc < kend; kc += 128) {
    asm volatile("s_waitcnt vmcnt(8)" ::: "memory");
    BBAR()
    COMPUTE(0)
    asm volatile("s_waitcnt lgkmcnt(0)" ::: "memory");
    BBAR()
    if (kc + 128 < kend) {
      STAGE(0, kc + 128)
      asm volatile("s_waitcnt vmcnt(8)" ::: "memory");
    } else {
      asm volatile("s_waitcnt vmcnt(0)" ::: "memory");
    }
    BBAR()
    COMPUTE(1)
    if (kc + 192 < kend) {
      asm volatile("s_waitcnt lgkmcnt(0)" ::: "memory");
      BBAR()
      STAGE(1, kc + 192)
    }
  }
#undef STAGE
#undef COMPUTE
#undef BBAR

#pragma unroll
  for (int i = 0; i < 4; ++i)
#pragma unroll
    for (int j = 0; j < 4; ++j)
#pragma unroll
      for (int rr = 0; rr < 4; ++rr) {
        const int row = m0 + wm + i * 16 + quad * 4 + rr;
        const int col = n0 + wn + j * 16 + lrow;
        CP[(size_t)row * NN + col] = acc[i][j][rr];
      }
}

// ---------------------------------------------------------------------------
// mono: all 10 stages in one dispatch, software grid barriers between.
// 512 blocks x 256 thr, 64 KiB LDS -> exactly 2 blocks/CU, all co-resident.
// ---------------------------------------------------------------------------
__global__ __launch_bounds__(256, 2) void mono(const void* __restrict__ xraw,
                                               const ushort* __restrict__ Sraw,
                                               char* __restrict__ ws,
                                               void* __restrict__ outv) {
  __shared__ ushort shg[4][8192];   // 64 KiB; aliased per stage
  ushort* sh = &shg[0][0];
  const int t = threadIdx.x;
  const int bid = blockIdx.x;
  const int f32 = *(const int*)ws;          // published by pre_kernel
  int* cnt = (int*)(ws + OFF_BAR);
  const float* pb = (const float*)(ws + OFF_P);
  ushort* xc = (ushort*)(ws + OFF_XC);
  ushort* z1 = (ushort*)(ws + OFF_Z1);
  ushort* y1 = (ushort*)(ws + OFF_Y1);
  ushort* v1 = (ushort*)(ws + OFF_V1);
  float* CF = (float*)(ws + OFF_CF);
  ushort* St = (ushort*)(ws + OFF_ST);

  // ---- S1: convert x -> bf16 (1,048,576 elems; 4/thread x 2 passes) -------
#pragma unroll 1
  for (int it = 0; it < 2; ++it) {
    const int i = (it * 131072 + bid * 256 + t) * 4;
    if (f32) {
      float4 v = *(const float4*)((const float*)xraw + i);
      uint2 o;
      o.x = (uint)f2bf(v.x) | ((uint)f2bf(v.y) << 16);
      o.y = (uint)f2bf(v.z) | ((uint)f2bf(v.w) << 16);
      *(uint2*)&xc[i] = o;
    } else {
      *(uint2*)&xc[i] = *(const uint2*)((const ushort*)xraw + i);
    }
  }

  // ---- S2: transpose S[k][n] -> St[n][k] bf16; 16384 tiles, 32/block ------
  {
    uint(*tileU)[33] = (uint(*)[33])sh;
#pragma unroll 1
    for (int tt = bid; tt < 16384; tt += NBLK) {
      const int tn = (tt & 127) * 64;
      const int tk = (tt >> 7) * 64;
      __syncthreads();               // protect tile reuse
      {
        const int kp = t >> 3;
        const int c = (t & 7) * 8;
        if (f32) {
          const float* r0 =
              (const float*)Sraw + (size_t)(tk + 2 * kp) * NN + tn + c;
          float4 a0 = *(const float4*)r0;
          float4 a1 = *(const float4*)(r0 + 4);
          float4 b0 = *(const float4*)(r0 + NN);
          float4 b1 = *(const float4*)(r0 + NN + 4);
          tileU[c + 0][kp] = (uint)f2bf(a0.x) | ((uint)f2bf(b0.x) << 16);
          tileU[c + 1][kp] = (uint)f2bf(a0.y) | ((uint)f2bf(b0.y) << 16);
          tileU[c + 2][kp] = (uint)f2bf(a0.z) | ((uint)f2bf(b0.z) << 16);
          tileU[c + 3][kp] = (uint)f2bf(a0.w) | ((uint)f2bf(b0.w) << 16);
          tileU[c + 4][kp] = (uint)f2bf(a1.x) | ((uint)f2bf(b1.x) << 16);
          tileU[c + 5][kp] = (uint)f2bf(a1.y) | ((uint)f2bf(b1.y) << 16);
          tileU[c + 6][kp] = (uint)f2bf(a1.z) | ((uint)f2bf(b1.z) << 16);
          tileU[c + 7][kp] = (uint)f2bf(a1.w) | ((uint)f2bf(b1.w) << 16);
        } else {
          const ushort* r0 = Sraw + (size_t)(tk + 2 * kp) * NN + tn + c;
          uint4 ua = *(const uint4*)r0;
          uint4 ub = *(const uint4*)(r0 + NN);
          const ushort* apx = (const ushort*)&ua;
          const ushort* bpx = (const ushort*)&ub;
#pragma unroll
          for (int j = 0; j < 8; ++j)
            tileU[c + j][kp] = (uint)apx[j] | ((uint)bpx[j] << 16);
        }
      }
      __syncthreads();
      {
        const int n = t >> 2;
#pragma unroll
        for (int it = 0; it < 2; ++it) {
          const int q = (t & 3) + 4 * it;
          uint4 w;
          w.x = tileU[n][q * 4 + 0];
          w.y = tileU[n][q * 4 + 1];
          w.z = tileU[n][q * 4 + 2];
          w.w = tileU[n][q * 4 + 3];
          *(uint4*)&St[(size_t)(tn + n) * NN + tk + q * 8] = w;
        }
      }
    }
  }

  gridbar(cnt, 1);

  // ---- S3: G1 z1-partials = xc @ St^T (64 n-blocks x 8 ksplits) -----------
  gemm_stage(xc, St, CF + (size_t)(bid >> 6) * 1048576, 0, (bid & 63) * 128,
             (bid >> 6) * 1024, 1024, sh);
  gridbar(cnt, 2);

  // ---- S4: R1 reduce 8 slices -> z1 bf16 ----------------------------------
#pragma unroll 1
  for (int it = 0; it < 2; ++it) {
    const size_t i = (size_t)(it * 131072 + bid * 256 + t) * 4;
    float4 s = *(const float4*)&CF[i];
#pragma unroll
    for (int z = 1; z < 8; ++z) {
      float4 u = *(const float4*)&CF[(size_t)z * 1048576 + i];
      s.x += u.x; s.y += u.y; s.z += u.z; s.w += u.w;
    }
    uint2 o;
    o.x = (uint)f2bf(s.x) | ((uint)f2bf(s.y) << 16);
    o.y = (uint)f2bf(s.z) | ((uint)f2bf(s.w) << 16);
    *(uint2*)&z1[i] = o;
  }
  gridbar(cnt, 3);

  // ---- S5: G2 z2-partials = z1 @ St^T -------------------------------------
  gemm_stage(z1, St, CF + (size_t)(bid >> 6) * 1048576, 0, (bid & 63) * 128,
             (bid >> 6) * 1024, 1024, sh);
  gridbar(cnt, 4);

  // ---- S6: C1 combine1 -> y1 (2 nodes/thread) -----------------------------
  {
    float* hs = (float*)sh;            // 96
    float* bs = hs + 96;               // 8
    if (t < 96) hs[t] = pb[PO_H1 + t];
    if (t < 8) bs[t] = pb[PO_B1 + t];
    __syncthreads();
    const int idx = bid * 256 + t;
    const int bt = idx >> 12;
    const int n2 = (idx & 4095) * 2;
    float acc[8][2];
#pragma unroll
    for (int g = 0; g < 8; ++g) { acc[g][0] = bs[g]; acc[g][1] = bs[g]; }
#pragma unroll
    for (int k = 0; k < 3; ++k)
#pragma unroll
      for (int f = 0; f < 4; ++f) {
        const size_t off = (size_t)(bt * 4 + f) * NN + n2;
        float v0, v1v;
        if (k == 2) {
          float2 w = *(const float2*)&CF[off];
#pragma unroll
          for (int z = 1; z < 8; ++z) {
            float2 u = *(const float2*)&CF[(size_t)z * 1048576 + off];
            w.x += u.x; w.y += u.y;
          }
          v0 = w.x; v1v = w.y;
        } else {
          const ushort* pp = (k == 0) ? xc : z1;
          uint w = *(const uint*)&pp[off];
          v0 = bf2f(w & 0xffff); v1v = bf2f(w >> 16);
        }
#pragma unroll
        for (int g = 0; g < 8; ++g) {
          const float hw = hs[(g * 3 + k) * 4 + f];
          acc[g][0] += hw * v0;
          acc[g][1] += hw * v1v;
        }
      }
#pragma unroll
    for (int g = 0; g < 8; ++g) {
      uint w = (uint)f2bf(tanhf(acc[g][0])) |
               ((uint)f2bf(tanhf(acc[g][1])) << 16);
      *(uint*)&y1[(size_t)(bt * 8 + g) * NN + n2] = w;
    }
  }
  gridbar(cnt, 5);

  // ---- S7: G3 v1-partials = y1 @ St^T (64 n x 2 m x 4 ksplits) ------------
  gemm_stage(y1, St, CF + (size_t)(bid >> 7) * 2097152, ((bid >> 6) & 1) * 128,
             (bid & 63) * 128, (bid >> 7) * 2048, 2048, sh);
  gridbar(cnt, 6);

  // ---- S8: R2 reduce 4 slices -> v1 bf16 ----------------------------------
#pragma unroll 1
  for (int it = 0; it < 4; ++it) {
    const size_t i = (size_t)(it * 131072 + bid * 256 + t) * 4;
    float4 s = *(const float4*)&CF[i];
#pragma unroll
    for (int z = 1; z < 4; ++z) {
      float4 u = *(const float4*)&CF[(size_t)z * 2097152 + i];
      s.x += u.x; s.y += u.y; s.z += u.z; s.w += u.w;
    }
    uint2 o;
    o.x = (uint)f2bf(s.x) | ((uint)f2bf(s.y) << 16);
    o.y = (uint)f2bf(s.z) | ((uint)f2bf(s.w) << 16);
    *(uint2*)&v1[i] = o;
  }
  gridbar(cnt, 7);

  // ---- S9: G4 v2-partials = v1 @ St^T -------------------------------------
  gemm_stage(v1, St, CF + (size_t)(bid >> 7) * 2097152, ((bid >> 6) & 1) * 128,
             (bid & 63) * 128, (bid >> 7) * 2048, 2048, sh);
  gridbar(cnt, 8);

  // ---- S10: C2 combine2 + readout -> out ----------------------------------
  {
    float* h2s = (float*)sh;            // 192
    float* W1s = h2s + 192;             // 64
    float* W2s = W1s + 64;              // 32
    float* b2s = W2s + 32;              // 8
    float* bw1s = b2s + 8;              // 8
    float* bw2s = bw1s + 8;             // 4
    if (t < 192) h2s[t] = pb[PO_H2 + t];
    if (t < 64) W1s[t] = pb[PO_W1 + t];
    if (t < 32) W2s[t] = pb[PO_W2 + t];
    if (t < 8) { b2s[t] = pb[PO_B2 + t]; bw1s[t] = pb[PO_BW1 + t]; }
    if (t < 4) bw2s[t] = pb[PO_BW2 + t];
    __syncthreads();
    const int idx = bid * 256 + t;
    const int bt = idx >> 12;
    const int n2 = (idx & 4095) * 2;
    float acc[8][2];
#pragma unroll
    for (int g = 0; g < 8; ++g) { acc[g][0] = b2s[g]; acc[g][1] = b2s[g]; }
#pragma unroll
    for (int k = 0; k < 3; ++k)
#pragma unroll
      for (int g1 = 0; g1 < 8; ++g1) {
        const size_t off = (size_t)(bt * 8 + g1) * NN + n2;
        float v0, v1v;
        if (k == 2) {
          float2 w = *(const float2*)&CF[off];
#pragma unroll
          for (int z = 1; z < 4; ++z) {
            float2 u = *(const float2*)&CF[(size_t)z * 2097152 + off];
            w.x += u.x; w.y += u.y;
          }
          v0 = w.x; v1v = w.y;
        } else {
          const ushort* pp = (k == 0) ? y1 : v1;
          uint w = *(const uint*)&pp[off];
          v0 = bf2f(w & 0xffff); v1v = bf2f(w >> 16);
        }
#pragma unroll
        for (int g2 = 0; g2 < 8; ++g2) {
          const float hw = h2s[(g2 * 3 + k) * 8 + g1];
          acc[g2][0] += hw * v0;
          acc[g2][1] += hw * v1v;
        }
      }
#pragma unroll
    for (int g = 0; g < 8; ++g) {
      acc[g][0] = tanhf(acc[g][0]);
      acc[g][1] = tanhf(acc[g][1]);
    }
    float o[4][2];
#pragma unroll
    for (int e = 0; e < 4; ++e) { o[e][0] = bw2s[e]; o[e][1] = bw2s[e]; }
#pragma unroll
    for (int d = 0; d < 8; ++d) {
      float s0 = bw1s[d], s1 = bw1s[d];
#pragma unroll
      for (int f = 0; f < 8; ++f) {
        const float w = W1s[d * 8 + f];
        s0 += w * acc[f][0];
        s1 += w * acc[f][1];
      }
      s0 = tanhf(s0);
      s1 = tanhf(s1);
#pragma unroll
      for (int e = 0; e < 4; ++e) {
        const float w = W2s[e * 8 + d];
        o[e][0] += w * s0;
        o[e][1] += w * s1;
      }
    }
#pragma unroll
    for (int e = 0; e < 4; ++e) {
      const size_t off = (size_t)(bt * 4 + e) * NN + n2;
      if (f32) {
        float2 w = {o[e][0], o[e][1]};
        *(float2*)&((float*)outv)[off] = w;
      } else {
        uint w = (uint)f2bf(o[e][0]) | ((uint)f2bf(o[e][1]) << 16);
        *(uint*)&((ushort*)outv)[off] = w;
      }
    }
  }
}

// ---------------------------------------------------------------------------
extern "C" void kernel_launch(void* const* d_in, const int* in_sizes, int n_in,
                              void* d_out, int out_size, void* d_ws,
                              size_t ws_size, hipStream_t stream) {
  (void)in_sizes; (void)n_in; (void)out_size; (void)ws_size;
  const void* x = d_in[0];
  const ushort* S = (const ushort*)d_in[1];   // raw bytes; dtype detected
  char* ws = (char*)d_ws;

  pre_kernel<<<1, 256, 0, stream>>>(S, d_in[2], d_in[3], d_in[4], d_in[5],
                                    d_in[6], d_in[7], d_in[8], d_in[9], ws);
  mono<<<NBLK, 256, 0, stream>>>(x, S, ws, (void*)d_out);
}

// Round 5
// 768.107 us; speedup vs baseline: 1.7557x; 1.7557x over previous
//
#include <hip/hip_runtime.h>
#include <math.h>

// Problem dims (fixed): B*T=32, N=8192, F0=4, F1=8, F2=8, K=3, D0=8, D1=4
constexpr int NN = 8192;

typedef short bh8 __attribute__((ext_vector_type(8)));    // 8 bf16 (4 VGPRs)
typedef float fl4 __attribute__((ext_vector_type(4)));    // 4 fp32 acc

__device__ __forceinline__ float bf2f(ushort h) {
  return __uint_as_float(((uint)h) << 16);
}
__device__ __forceinline__ ushort f2bf(float f) {
  uint u = __float_as_uint(f);
  return (ushort)((u + 0x7fffu + ((u >> 16) & 1u)) >> 16);  // RNE
}

// ---- workspace layout (bytes); ws >= 1 GiB, poisoned each iteration --------
constexpr size_t OFF_P  = 16;                    // 412 fp32 canonical params
constexpr size_t OFF_TK = 2048;                  // 512 int fan-in tickets
constexpr size_t OFF_XC = 4096;                  // x bf16 [128][8192]  2 MiB
constexpr size_t OFF_Z1 = OFF_XC + 2097152;      // z1 bf16 [128][8192] 2 MiB
constexpr size_t OFF_Y1 = OFF_Z1 + 2097152;      // y1 bf16 [256][8192] 4 MiB
constexpr size_t OFF_V1 = OFF_Y1 + 4194304;      // v1 bf16 [256][8192] 4 MiB
constexpr size_t OFF_ST = 33554432;              // St bf16 [8192][8192] 128 MiB
constexpr size_t OFF_CF = 167772160;             // CF fp32 partials 32 MiB
constexpr size_t OFF_V2 = 201326592;             // v2 fp32 reduced     8 MiB

// param-block offsets (in floats)
constexpr int PO_H1 = 0, PO_B1 = 96, PO_H2 = 104, PO_B2 = 296;
constexpr int PO_W1 = 304, PO_BW1 = 368, PO_W2 = 376, PO_BW2 = 408;

// ---------------------------------------------------------------------------
// pre: detect dtype (fp32 vs bf16) from S bytes; canonicalize params; zero
// the 512 fan-in tickets (ws is poison-filled every iteration).
// ---------------------------------------------------------------------------
__global__ __launch_bounds__(256) void pre_kernel(
    const ushort* __restrict__ Sraw,
    const void* h1, const void* b1, const void* h2, const void* b2,
    const void* W1, const void* bw1, const void* W2, const void* bw2,
    char* __restrict__ ws) {
  __shared__ int smax[256];
  __shared__ int sflag;
  const int t = threadIdx.x;
  int mx = 0;
  for (int k = 0; k < 32; ++k) {
    ushort u = Sraw[(size_t)(t * 32 + k) * 2];
    int e = (u >> 7) & 0xff;
    mx = mx > e ? mx : e;
  }
  smax[t] = mx;
  __syncthreads();
  for (int s = 128; s > 0; s >>= 1) {
    if (t < s) smax[t] = smax[t] > smax[t + s] ? smax[t] : smax[t + s];
    __syncthreads();
  }
  if (t == 0) {
    sflag = (smax[0] >= 0x90) ? 1 : 0;
    *(int*)ws = sflag;
  }
  __syncthreads();
  // zero fan-in tickets
  int* tk = (int*)(ws + OFF_TK);
  tk[t] = 0;
  tk[256 + t] = 0;
  const int f32 = sflag;
  float* pb = (float*)(ws + OFF_P);
  const void* ptrs[8] = {h1, b1, h2, b2, W1, bw1, W2, bw2};
  const int offs[8] = {PO_H1, PO_B1, PO_H2, PO_B2, PO_W1, PO_BW1, PO_W2, PO_BW2};
  const int lens[8] = {96, 8, 192, 8, 64, 8, 32, 4};
  for (int idx = t; idx < 412; idx += 256) {
#pragma unroll
    for (int s = 0; s < 8; ++s) {
      if (idx >= offs[s] && idx < offs[s] + lens[s]) {
        const int j = idx - offs[s];
        pb[idx] = f32 ? ((const float*)ptrs[s])[j]
                      : bf2f(((const ushort*)ptrs[s])[j]);
      }
    }
  }
}

// ---------------------------------------------------------------------------
// Transpose S[k][n] -> St[n][k] (bf16), 64x64 tiles; first 1024 blocks also
// convert x -> bf16 (fused; saves one dispatch).
// ---------------------------------------------------------------------------
__global__ __launch_bounds__(256) void transpose_cvt(
    const ushort* __restrict__ Sraw, const void* __restrict__ xraw,
    const char* __restrict__ wsro, ushort* __restrict__ St,
    ushort* __restrict__ xc) {
  __shared__ uint tileU[64][33];
  const int f32 = *(const int*)wsro;
  const int t = threadIdx.x;
  const int bid = blockIdx.y * gridDim.x + blockIdx.x;
  if (bid < 1024) {  // fused x-convert: 1M elems, 4/thread
    const int i = (bid * 256 + t) * 4;
    if (f32) {
      float4 v = *(const float4*)((const float*)xraw + i);
      uint2 o;
      o.x = (uint)f2bf(v.x) | ((uint)f2bf(v.y) << 16);
      o.y = (uint)f2bf(v.z) | ((uint)f2bf(v.w) << 16);
      *(uint2*)&xc[i] = o;
    } else {
      *(uint2*)&xc[i] = *(const uint2*)((const ushort*)xraw + i);
    }
  }
  const int tn = blockIdx.x * 64;   // node (output-row) tile
  const int tk = blockIdx.y * 64;   // k tile
  {
    const int kp = t >> 3;          // 0..31 k-pair
    const int c  = (t & 7) * 8;     // 0..56 node offset
    if (f32) {
      const float* r0 = (const float*)Sraw + (size_t)(tk + 2 * kp) * NN + tn + c;
      float4 a0 = *(const float4*)r0;
      float4 a1 = *(const float4*)(r0 + 4);
      float4 b0 = *(const float4*)(r0 + NN);
      float4 b1 = *(const float4*)(r0 + NN + 4);
      tileU[c + 0][kp] = (uint)f2bf(a0.x) | ((uint)f2bf(b0.x) << 16);
      tileU[c + 1][kp] = (uint)f2bf(a0.y) | ((uint)f2bf(b0.y) << 16);
      tileU[c + 2][kp] = (uint)f2bf(a0.z) | ((uint)f2bf(b0.z) << 16);
      tileU[c + 3][kp] = (uint)f2bf(a0.w) | ((uint)f2bf(b0.w) << 16);
      tileU[c + 4][kp] = (uint)f2bf(a1.x) | ((uint)f2bf(b1.x) << 16);
      tileU[c + 5][kp] = (uint)f2bf(a1.y) | ((uint)f2bf(b1.y) << 16);
      tileU[c + 6][kp] = (uint)f2bf(a1.z) | ((uint)f2bf(b1.z) << 16);
      tileU[c + 7][kp] = (uint)f2bf(a1.w) | ((uint)f2bf(b1.w) << 16);
    } else {
      const ushort* r0 = Sraw + (size_t)(tk + 2 * kp) * NN + tn + c;
      uint4 ua = *(const uint4*)r0;
      uint4 ub = *(const uint4*)(r0 + NN);
      const ushort* ap = (const ushort*)&ua;
      const ushort* bp = (const ushort*)&ub;
#pragma unroll
      for (int j = 0; j < 8; ++j)
        tileU[c + j][kp] = (uint)ap[j] | ((uint)bp[j] << 16);
    }
  }
  __syncthreads();
  {
    const int n = t >> 2;           // 0..63
#pragma unroll
    for (int it = 0; it < 2; ++it) {
      const int q = (t & 3) + 4 * it;   // 0..7 (8 k-elements each)
      uint4 w;
      w.x = tileU[n][q * 4 + 0];
      w.y = tileU[n][q * 4 + 1];
      w.z = tileU[n][q * 4 + 2];
      w.w = tileU[n][q * 4 + 3];
      *(uint4*)&St[(size_t)(tn + n) * NN + tk + q * 8] = w;
    }
  }
}

// ---------------------------------------------------------------------------
// GEMM with fan-in epilogue. Main loop identical to round-3 (verified):
// m97 shape, 4 waves (2x2), 64x64/wave, acc[4][4], BK=64 double-buffer,
// XOR-granule DMA staging, counted-vmcnt pipeline. After partial stores,
// a device-scope ticket elects the LAST k-split block per output tile to
// reduce all Z slices (exact z-order -> bit-identical):
//   MODE 0: reduce -> bf16 OUT           (G1 -> z1, G3 -> v1)
//   MODE 1: reduce -> fp32 OUT           (G4 -> v2)
//   MODE 2: reduce -> LDS, run combine1 in-place -> y1 (G2; z2 never in HBM)
// No spins anywhere -> no hang risk; a sync bug surfaces as absmax FAIL.
// ---------------------------------------------------------------------------
template <int KR, int Z, int MODE>
__global__ __launch_bounds__(256, 2) void gemm_t(
    const ushort* __restrict__ A, const ushort* __restrict__ St,
    float* __restrict__ CF, void* __restrict__ OUT,
    const ushort* __restrict__ T0, const ushort* __restrict__ T1,
    char* __restrict__ ws, int tkBase) {
  __shared__ ushort sh[32768];   // As: [0,16384), Bs: [16384,32768) (2 bufs)
  __shared__ float prm[104];
  __shared__ int lastFlag;
  const int tid = threadIdx.x;
  const int wave = tid >> 6, lane = tid & 63;
  const int lrow = lane & 15, quad = lane >> 4;
  const int m0 = blockIdx.y * 128;
  const int n0 = blockIdx.x * 128;
  const int kc0 = blockIdx.z * KR;
  const int wm = (wave & 1) * 64;
  const int wn = (wave >> 1) * 64;
  float* CP = CF + (size_t)blockIdx.z * (size_t)(gridDim.y * 128) * NN;

  const ushort* ap[4];
  const ushort* bp[4];
#pragma unroll
  for (int r = 0; r < 4; ++r) {
    const int s = r * 256 + tid;
    const int row = s >> 3, g = (s & 7) ^ (row & 7);
    ap[r] = A + (size_t)(m0 + row) * NN + g * 8;
    bp[r] = St + (size_t)(n0 + row) * NN + g * 8;
  }

  fl4 acc[4][4];
#pragma unroll
  for (int i = 0; i < 4; ++i)
#pragma unroll
    for (int j = 0; j < 4; ++j) acc[i][j] = (fl4){0.f, 0.f, 0.f, 0.f};

#define STAGE(buf, kc)                                                         \
  {                                                                            \
    _Pragma("unroll")                                                          \
    for (int r = 0; r < 4; ++r) {                                              \
      __builtin_amdgcn_global_load_lds(                                        \
          (__attribute__((address_space(1))) void*)(ap[r] + (kc)),             \
          (__attribute__((address_space(3))) void*)                            \
              &sh[(buf) * 8192 + (r * 256 + wave * 64) * 8],                   \
          16, 0, 0);                                                           \
      __builtin_amdgcn_global_load_lds(                                        \
          (__attribute__((address_space(1))) void*)(bp[r] + (kc)),             \
          (__attribute__((address_space(3))) void*)                            \
              &sh[16384 + (buf) * 8192 + (r * 256 + wave * 64) * 8],           \
          16, 0, 0);                                                           \
    }                                                                          \
  }

#define COMPUTE(buf)                                                           \
  {                                                                            \
    _Pragma("unroll")                                                          \
    for (int is = 0; is < 2; ++is) {                                           \
      bh8 af[4], bf[4];                                                        \
      const int G = is * 4 + quad;                                             \
      _Pragma("unroll")                                                        \
      for (int i = 0; i < 4; ++i) {                                            \
        const int row = wm + i * 16 + lrow;                                    \
        af[i] = *(const bh8*)&sh[(buf) * 8192 + row * 64 +                     \
                                 ((G ^ (row & 7)) * 8)];                       \
      }                                                                        \
      _Pragma("unroll")                                                        \
      for (int j = 0; j < 4; ++j) {                                            \
        const int row = wn + j * 16 + lrow;                                    \
        bf[j] = *(const bh8*)&sh[16384 + (buf) * 8192 + row * 64 +             \
                                 ((G ^ (row & 7)) * 8)];                       \
      }                                                                        \
      _Pragma("unroll")                                                        \
      for (int i = 0; i < 4; ++i)                                              \
        _Pragma("unroll")                                                      \
        for (int j = 0; j < 4; ++j)                                            \
          acc[i][j] = __builtin_amdgcn_mfma_f32_16x16x32_bf16(af[i], bf[j],    \
                                                              acc[i][j], 0, 0, 0); \
    }                                                                          \
  }

#define BBAR()                                                                 \
  {                                                                            \
    asm volatile("" ::: "memory");                                             \
    __builtin_amdgcn_s_barrier();                                              \
    asm volatile("" ::: "memory");                                             \
  }

  STAGE(0, kc0)
  STAGE(1, kc0 + 64)
  const int kend = kc0 + KR;
#pragma unroll 1
  for (int kc = kc0; kc < kend; kc += 128) {
    asm volatile("s_waitcnt vmcnt(8)" ::: "memory");
    BBAR()
    COMPUTE(0)
    asm volatile("s_waitcnt lgkmcnt(0)" ::: "memory");
    BBAR()
    if (kc + 128 < kend) {
      STAGE(0, kc + 128)
      asm volatile("s_waitcnt vmcnt(8)" ::: "memory");
    } else {
      asm volatile("s_waitcnt vmcnt(0)" ::: "memory");
    }
    BBAR()
    COMPUTE(1)
    if (kc + 192 < kend) {
      asm volatile("s_waitcnt lgkmcnt(0)" ::: "memory");
      BBAR()
      STAGE(1, kc + 192)
    }
  }
#undef STAGE
#undef COMPUTE
#undef BBAR

  // partial stores (plain; slice written exactly once)
#pragma unroll
  for (int i = 0; i < 4; ++i)
#pragma unroll
    for (int j = 0; j < 4; ++j)
#pragma unroll
      for (int rr = 0; rr < 4; ++rr) {
        const int row = m0 + wm + i * 16 + quad * 4 + rr;
        const int col = n0 + wn + j * 16 + lrow;
        CP[(size_t)row * NN + col] = acc[i][j][rr];
      }

  // ---- fan-in: last k-split block per tile reduces ------------------------
  __syncthreads();
  const int tileId = blockIdx.y * gridDim.x + blockIdx.x;
  int* ticket = (int*)(ws + OFF_TK) + tkBase + tileId;
  if (tid == 0) {
    __threadfence();   // release: partials visible device-wide
    int old = __hip_atomic_fetch_add(ticket, 1, __ATOMIC_ACQ_REL,
                                     __HIP_MEMORY_SCOPE_AGENT);
    lastFlag = (old == Z - 1) ? 1 : 0;
  }
  __syncthreads();
  if (!lastFlag) return;
  __threadfence();     // acquire: see all other blocks' partials

  const size_t SLST = (size_t)gridDim.y * 128 * NN;
  if constexpr (MODE == 2) {
    // reduce z2 tile into LDS (64 KiB), then combine1 in-place -> y1
    float* zl = (float*)sh;
    const float* pb = (const float*)(ws + OFF_P);
    for (int e = tid; e < 4096; e += 256) {
      const int row = e >> 5;
      const int c = (e & 31) * 4;
      const size_t base = (size_t)row * NN + n0 + c;   // m0 == 0 for MODE 2
      float4 s = *(const float4*)&CF[base];
#pragma unroll
      for (int z = 1; z < Z; ++z) {
        float4 u = *(const float4*)&CF[(size_t)z * SLST + base];
        s.x += u.x; s.y += u.y; s.z += u.z; s.w += u.w;
      }
      *(float4*)&zl[row * 128 + c] = s;
    }
    if (tid < 96) prm[tid] = pb[PO_H1 + tid];
    if (tid < 8) prm[96 + tid] = pb[PO_B1 + tid];
    __syncthreads();
    ushort* y1o = (ushort*)OUT;
    const int nl = (tid & 63) * 2;
#pragma unroll 1
    for (int p = 0; p < 8; ++p) {
      const int bt = p * 4 + (tid >> 6);
      float a2[8][2];
#pragma unroll
      for (int g = 0; g < 8; ++g) { a2[g][0] = prm[96 + g]; a2[g][1] = prm[96 + g]; }
#pragma unroll
      for (int k = 0; k < 3; ++k)
#pragma unroll
        for (int f = 0; f < 4; ++f) {
          const int row = bt * 4 + f;
          float v0, v1v;
          if (k == 2) {
            v0 = zl[row * 128 + nl];
            v1v = zl[row * 128 + nl + 1];
          } else {
            const ushort* pp = (k == 0) ? T0 : T1;
            uint w = *(const uint*)&pp[(size_t)row * NN + n0 + nl];
            v0 = bf2f(w & 0xffff);
            v1v = bf2f(w >> 16);
          }
#pragma unroll
          for (int g = 0; g < 8; ++g) {
            const float hw = prm[(g * 3 + k) * 4 + f];
            a2[g][0] += hw * v0;
            a2[g][1] += hw * v1v;
          }
        }
#pragma unroll
      for (int g = 0; g < 8; ++g) {
        uint w = (uint)f2bf(tanhf(a2[g][0])) |
                 ((uint)f2bf(tanhf(a2[g][1])) << 16);
        *(uint*)&y1o[(size_t)(bt * 8 + g) * NN + n0 + nl] = w;
      }
    }
  } else {
    // plain reduce: Z slices -> bf16 (MODE 0) or fp32 (MODE 1)
    for (int e = tid; e < 4096; e += 256) {
      const int row = e >> 5;
      const int c = (e & 31) * 4;
      const size_t base = (size_t)(m0 + row) * NN + n0 + c;
      float4 s = *(const float4*)&CF[base];
#pragma unroll
      for (int z = 1; z < Z; ++z) {
        float4 u = *(const float4*)&CF[(size_t)z * SLST + base];
        s.x += u.x; s.y += u.y; s.z += u.z; s.w += u.w;
      }
      if constexpr (MODE == 0) {
        uint2 o;
        o.x = (uint)f2bf(s.x) | ((uint)f2bf(s.y) << 16);
        o.y = (uint)f2bf(s.z) | ((uint)f2bf(s.w) << 16);
        *(uint2*)&((ushort*)OUT)[base] = o;
      } else {
        *(float4*)&((float*)OUT)[base] = s;
      }
    }
  }
}

// ---------------------------------------------------------------------------
// combine2: y2 = tanh(b2 + sum h2*{y1,v1,v2}); readout W1/tanh/W2.
// v2 is the REDUCED fp32 buffer (single slice) from G4's fan-in.
// ---------------------------------------------------------------------------
__global__ __launch_bounds__(256) void combine2(const ushort* __restrict__ y1,
                                                const ushort* __restrict__ v1,
                                                const float* __restrict__ v2f,
                                                const char* __restrict__ wsro,
                                                void* __restrict__ outv) {
  const float* pb = (const float*)(wsro + OFF_P);
  const int f32 = *(const int*)wsro;
  __shared__ float h2s[192], W1s[64], W2s[32], b2s[8], bw1s[8], bw2s[4];
  const int t = threadIdx.x;
  if (t < 192) h2s[t] = pb[PO_H2 + t];
  if (t < 64) W1s[t] = pb[PO_W1 + t];
  if (t < 32) W2s[t] = pb[PO_W2 + t];
  if (t < 8) { b2s[t] = pb[PO_B2 + t]; bw1s[t] = pb[PO_BW1 + t]; }
  if (t < 4) bw2s[t] = pb[PO_BW2 + t];
  __syncthreads();
  const int idx = blockIdx.x * 256 + t;
  const int bt = idx >> 12;
  const int n2 = (idx & 4095) * 2;
  float acc[8][2];
#pragma unroll
  for (int g = 0; g < 8; ++g) { acc[g][0] = b2s[g]; acc[g][1] = b2s[g]; }
#pragma unroll
  for (int k = 0; k < 3; ++k)
#pragma unroll
    for (int g1 = 0; g1 < 8; ++g1) {
      const size_t off = (size_t)(bt * 8 + g1) * NN + n2;
      float v0, v1v;
      if (k == 2) {
        float2 w = *(const float2*)&v2f[off];
        v0 = w.x; v1v = w.y;
      } else {
        const ushort* pp = (k == 0) ? y1 : v1;
        uint w = *(const uint*)&pp[off];
        v0 = bf2f(w & 0xffff); v1v = bf2f(w >> 16);
      }
#pragma unroll
      for (int g2 = 0; g2 < 8; ++g2) {
        const float hw = h2s[(g2 * 3 + k) * 8 + g1];
        acc[g2][0] += hw * v0;
        acc[g2][1] += hw * v1v;
      }
    }
#pragma unroll
  for (int g = 0; g < 8; ++g) {
    acc[g][0] = tanhf(acc[g][0]);
    acc[g][1] = tanhf(acc[g][1]);
  }
  float o[4][2];
#pragma unroll
  for (int e = 0; e < 4; ++e) { o[e][0] = bw2s[e]; o[e][1] = bw2s[e]; }
#pragma unroll
  for (int d = 0; d < 8; ++d) {
    float s0 = bw1s[d], s1 = bw1s[d];
#pragma unroll
    for (int f = 0; f < 8; ++f) {
      const float w = W1s[d * 8 + f];
      s0 += w * acc[f][0];
      s1 += w * acc[f][1];
    }
    s0 = tanhf(s0);
    s1 = tanhf(s1);
#pragma unroll
    for (int e = 0; e < 4; ++e) {
      const float w = W2s[e * 8 + d];
      o[e][0] += w * s0;
      o[e][1] += w * s1;
    }
  }
#pragma unroll
  for (int e = 0; e < 4; ++e) {
    const size_t off = (size_t)(bt * 4 + e) * NN + n2;
    if (f32) {
      float2 w = {o[e][0], o[e][1]};
      *(float2*)&((float*)outv)[off] = w;
    } else {
      uint w = (uint)f2bf(o[e][0]) | ((uint)f2bf(o[e][1]) << 16);
      *(uint*)&((ushort*)outv)[off] = w;
    }
  }
}

// ---------------------------------------------------------------------------
extern "C" void kernel_launch(void* const* d_in, const int* in_sizes, int n_in,
                              void* d_out, int out_size, void* d_ws,
                              size_t ws_size, hipStream_t stream) {
  (void)in_sizes; (void)n_in; (void)out_size; (void)ws_size;
  const void* x = d_in[0];
  const ushort* S = (const ushort*)d_in[1];   // raw bytes; dtype detected
  char* ws = (char*)d_ws;
  ushort* xc = (ushort*)(ws + OFF_XC);
  ushort* z1 = (ushort*)(ws + OFF_Z1);
  ushort* y1 = (ushort*)(ws + OFF_Y1);
  ushort* v1 = (ushort*)(ws + OFF_V1);
  float* CF = (float*)(ws + OFF_CF);
  float* v2 = (float*)(ws + OFF_V2);
  ushort* St = (ushort*)(ws + OFF_ST);

  pre_kernel<<<1, 256, 0, stream>>>(S, d_in[2], d_in[3], d_in[4], d_in[5],
                                    d_in[6], d_in[7], d_in[8], d_in[9], ws);
  transpose_cvt<<<dim3(128, 128), 256, 0, stream>>>(S, x, ws, St, xc);

  // G1: z1-partials = xc @ St^T ; fan-in reduce -> z1 bf16
  gemm_t<1024, 8, 0><<<dim3(64, 1, 8), 256, 0, stream>>>(
      xc, St, CF, (void*)z1, nullptr, nullptr, ws, 0);
  // G2: z2-partials = z1 @ St^T ; fan-in reduce -> LDS -> combine1 -> y1
  gemm_t<1024, 8, 2><<<dim3(64, 1, 8), 256, 0, stream>>>(
      z1, St, CF, (void*)y1, xc, z1, ws, 128);
  // G3: v1-partials = y1 @ St^T ; fan-in reduce -> v1 bf16
  gemm_t<2048, 4, 0><<<dim3(64, 2, 4), 256, 0, stream>>>(
      y1, St, CF, (void*)v1, nullptr, nullptr, ws, 256);
  // G4: v2-partials = v1 @ St^T ; fan-in reduce -> v2 fp32
  gemm_t<2048, 4, 1><<<dim3(64, 2, 4), 256, 0, stream>>>(
      v1, St, CF, (void*)v2, nullptr, nullptr, ws, 384);
  combine2<<<512, 256, 0, stream>>>(y1, v1, v2, ws, (void*)d_out);
}